// Round 12
// baseline (171.331 us; speedup 1.0000x reference)
//
#include <hip/hip_runtime.h>
#include <math.h>

static constexpr int B  = 8;
static constexpr int T  = 800;
static constexpr int L  = 192000;
static constexpr int NB = 24;
static constexpr float SCALE = 800.0f / 192000.0f;  // T/L

typedef __bf16 bf8 __attribute__((ext_vector_type(8)));
typedef float  f4  __attribute__((ext_vector_type(4)));

__device__ __forceinline__ float sigf(float x) { return 1.0f / (1.0f + __expf(-x)); }
__device__ __forceinline__ float leaky(float x) { return x >= 0.0f ? x : 0.1f * x; }
__device__ __forceinline__ unsigned short f2bf(float f) {
    unsigned u = __float_as_uint(f);
    u = u + 0x7FFFu + ((u >> 16) & 1u);
    return (unsigned short)(u >> 16);
}
__device__ __forceinline__ float bflo(unsigned u) { return __uint_as_float(u << 16); }
__device__ __forceinline__ float bfhi(unsigned u) { return __uint_as_float(u & 0xffff0000u); }

__device__ __forceinline__ void interp_idx(int l, int& i0, int& i1, float& w) {
    float pos = ((float)l + 0.5f) * SCALE - 0.5f;
    pos = fminf(fmaxf(pos, 0.0f), (float)(T - 1));
    i0 = (int)pos;
    i1 = min(i0 + 1, T - 1);
    w = pos - (float)i0;
}

// ---- weight transpose+cast: conv weights -> [tap][cout][cin] bf16 ----
__global__ __launch_bounds__(256) void k_twm(const float* __restrict__ w1,
                                             const float* __restrict__ w2,
                                             const float* __restrict__ wss,
                                             unsigned short* __restrict__ wT1,
                                             unsigned short* __restrict__ wT2,
                                             unsigned short* __restrict__ wTs) {
    int idx = blockIdx.x * 256 + threadIdx.x;
    if (idx < 98304) {                        // np_w1 [256][128][3]
        int tap = idx / (256 * 128), r = idx % (256 * 128);
        int cout = r / 128, cin = r % 128;
        wT1[idx] = f2bf(w1[(cout * 128 + cin) * 3 + tap]);
    } else if (idx < 98304 + 196608) {        // np_w2 [256][256][3]
        int j = idx - 98304;
        int tap = j / (256 * 256), r = j % (256 * 256);
        int cout = r / 256, cin = r % 256;
        wT2[j] = f2bf(w2[(cout * 256 + cin) * 3 + tap]);
    } else if (idx < 98304 + 196608 + 49152) {// ss_w1 [128][128][3]
        int j = idx - 294912;
        int tap = j / (128 * 128), r = j % (128 * 128);
        int cout = r / 128, cin = r % 128;
        wTs[j] = f2bf(wss[(cout * 128 + cin) * 3 + tap]);
    }
}

// ---- mega (512 thr / 8 waves, 32-col t-tile), 1D grid interleaving np/ss per XCD ----
union SMem {
    struct {
        unsigned short xs[50 * 136];     // cond cols t0-2 .. t0+47 (only ..t0+33 used)
        unsigned short h1s[34 * 264];    // h1 cols t0-1 .. t0+32 (zeroed outside [0,T))
        unsigned short h2s[32 * 264];    // h2 cols t0 .. t0+31
        float bnd[32][25];
    } np;
    struct {
        unsigned short xs[34 * 136];     // cond cols t0-1 .. t0+32
        unsigned short gs[32 * 136];
        float sv[32][5];
        float nws[32][5];
    } ss;
};

__global__ __launch_bounds__(512) void k_mega(const float* __restrict__ cond,
                                              const unsigned short* __restrict__ wT1,
                                              const float* __restrict__ b1,
                                              const unsigned short* __restrict__ wT2,
                                              const float* __restrict__ b2np,
                                              const float* __restrict__ w3,
                                              const float* __restrict__ b3,
                                              const float* __restrict__ fbw,
                                              const unsigned short* __restrict__ wTs,
                                              const float* __restrict__ bss,
                                              const float* __restrict__ w2ss,
                                              const float* __restrict__ b2ss,
                                              const float* __restrict__ ntf,
                                              float* __restrict__ h_all,
                                              float* __restrict__ g_all,
                                              float* __restrict__ attack,
                                              float* __restrict__ inten) {
    __shared__ SMem sm;
    // 1D grid 400: b = x&7 (8 XCD round-robin), quad = x>>3; chain = quad&1,
    // t-tile = quad>>1. Each XCD alternates heavy np / light ss blocks.
    const int bx = blockIdx.x;
    const int b = bx & 7;
    const int quad = bx >> 3;
    const int chain = quad & 1;
    const int t0 = (quad >> 1) * 32;
    const int tid = threadIdx.x;
    const int wave = tid >> 6, lane = tid & 63;   // 8 waves
    const int nfr = lane & 15;
    const int ko8 = (lane >> 4) * 8;
    const int rb = (lane >> 4) * 4;
    const int tcol = lane & 15;

    if (chain == 0) {
        // ================= NP chain =================
        for (int i = tid; i < 50 * 128; i += 512) {
            int cin = i / 50, j = i % 50;
            int t = t0 - 2 + j;
            sm.np.xs[j * 136 + cin] = (t >= 0 && t < T) ? f2bf(cond[(b * 128 + cin) * T + t])
                                                        : (unsigned short)0;
        }
        __syncthreads();
        const int coutb = wave * 32;    // 8 waves x 32 couts = 256
        // conv1: 3 n-tiles (output cols t0-1 .. t0+46; first 34 kept), 2 m/wave
        f4 a1[3][2] = {};
#pragma unroll
        for (int tap = 0; tap < 3; ++tap) {
            bf8 aw[2][4];
#pragma unroll
            for (int m = 0; m < 2; ++m)
#pragma unroll
                for (int q = 0; q < 4; ++q)
                    aw[m][q] = *reinterpret_cast<const bf8*>(
                        wT1 + ((tap * 256 + coutb + m * 16 + nfr) * 128 + q * 32 + ko8));
#pragma unroll
            for (int q = 0; q < 4; ++q) {
                bf8 bv0 = *reinterpret_cast<const bf8*>(&sm.np.xs[(nfr + tap) * 136 + q * 32 + ko8]);
                bf8 bv1 = *reinterpret_cast<const bf8*>(&sm.np.xs[(nfr + 16 + tap) * 136 + q * 32 + ko8]);
                bf8 bv2 = *reinterpret_cast<const bf8*>(&sm.np.xs[(nfr + 32 + tap) * 136 + q * 32 + ko8]);
#pragma unroll
                for (int m = 0; m < 2; ++m) {
                    a1[0][m] = __builtin_amdgcn_mfma_f32_16x16x32_bf16(aw[m][q], bv0, a1[0][m], 0, 0, 0);
                    a1[1][m] = __builtin_amdgcn_mfma_f32_16x16x32_bf16(aw[m][q], bv1, a1[1][m], 0, 0, 0);
                    a1[2][m] = __builtin_amdgcn_mfma_f32_16x16x32_bf16(aw[m][q], bv2, a1[2][m], 0, 0, 0);
                }
            }
        }
        // h1 -> LDS; cols outside [0,T) are EXACT zeros (conv2's zero padding)
#pragma unroll
        for (int nt = 0; nt < 3; ++nt) {
            int lcol = nt * 16 + tcol;
            if (lcol < 34) {
                int gcol = t0 - 1 + lcol;
                bool ok = (gcol >= 0 && gcol < T);
#pragma unroll
                for (int m = 0; m < 2; ++m) {
                    ushort4 pk;
                    if (ok) {
                        pk.x = f2bf(leaky(a1[nt][m][0] + b1[coutb + m * 16 + rb + 0]));
                        pk.y = f2bf(leaky(a1[nt][m][1] + b1[coutb + m * 16 + rb + 1]));
                        pk.z = f2bf(leaky(a1[nt][m][2] + b1[coutb + m * 16 + rb + 2]));
                        pk.w = f2bf(leaky(a1[nt][m][3] + b1[coutb + m * 16 + rb + 3]));
                    } else {
                        pk.x = pk.y = pk.z = pk.w = 0;
                    }
                    *reinterpret_cast<ushort4*>(&sm.np.h1s[lcol * 264 + coutb + m * 16 + rb]) = pk;
                }
            }
        }
        __syncthreads();
        // conv2: 256->256, 2 n-tiles x 2 m-tiles; per-tap batched A-loads
        f4 a2[2][2] = {};   // [nv][m]
#pragma unroll
        for (int tap = 0; tap < 3; ++tap) {
            bf8 aw[2][8];
#pragma unroll
            for (int m = 0; m < 2; ++m)
#pragma unroll
                for (int q = 0; q < 8; ++q)
                    aw[m][q] = *reinterpret_cast<const bf8*>(
                        wT2 + ((tap * 256 + coutb + m * 16 + nfr) * 256 + q * 32 + ko8));
#pragma unroll
            for (int q = 0; q < 8; ++q) {
                bf8 bv0 = *reinterpret_cast<const bf8*>(&sm.np.h1s[(nfr + tap) * 264 + q * 32 + ko8]);
                bf8 bv1 = *reinterpret_cast<const bf8*>(&sm.np.h1s[(nfr + 16 + tap) * 264 + q * 32 + ko8]);
#pragma unroll
                for (int m = 0; m < 2; ++m) {
                    a2[0][m] = __builtin_amdgcn_mfma_f32_16x16x32_bf16(aw[m][q], bv0, a2[0][m], 0, 0, 0);
                    a2[1][m] = __builtin_amdgcn_mfma_f32_16x16x32_bf16(aw[m][q], bv1, a2[1][m], 0, 0, 0);
                }
            }
        }
#pragma unroll
        for (int nv = 0; nv < 2; ++nv)
#pragma unroll
            for (int m = 0; m < 2; ++m) {
                ushort4 pk;
                pk.x = f2bf(leaky(a2[nv][m][0] + b2np[coutb + m * 16 + rb + 0]));
                pk.y = f2bf(leaky(a2[nv][m][1] + b2np[coutb + m * 16 + rb + 1]));
                pk.z = f2bf(leaky(a2[nv][m][2] + b2np[coutb + m * 16 + rb + 2]));
                pk.w = f2bf(leaky(a2[nv][m][3] + b2np[coutb + m * 16 + rb + 3]));
                *reinterpret_cast<ushort4*>(&sm.np.h2s[(nv * 16 + tcol) * 264 + coutb + m * 16 + rb]) = pk;
            }
        __syncthreads();
        // head in f32; item i -> (c = i>>5, t = i&31); 864 items
        for (int i = tid; i < 27 * 32; i += 512) {
            int c = i >> 5, t = i & 31;
            float s = b3[c];
            const unsigned short* hp = &sm.np.h2s[t * 264];
            const float* wp3 = w3 + c * 256;
#pragma unroll 4
            for (int kk = 0; kk < 256; kk += 8) {
                uint4 u = *reinterpret_cast<const uint4*>(hp + kk);
                float4 wa = *reinterpret_cast<const float4*>(wp3 + kk);
                float4 wb = *reinterpret_cast<const float4*>(wp3 + kk + 4);
                s += bflo(u.x) * wa.x + bfhi(u.x) * wa.y
                   + bflo(u.y) * wa.z + bfhi(u.y) * wa.w
                   + bflo(u.z) * wb.x + bfhi(u.z) * wb.y
                   + bflo(u.w) * wb.z + bfhi(u.w) * wb.w;
            }
            if (c < 24) sm.np.bnd[t][c] = sigf(s);
            else if (c == 24) attack[b * T + t0 + t] = sigf(s) * 10.0f;
            else if (c == 26) inten[b * T + t0 + t] = sigf(s);
        }
        __syncthreads();
        // h_all[b][k][t] = sum_c bnd[t][c] * fbw[c][k]; 992 items
        for (int i = tid; i < 31 * 32; i += 512) {
            int k = i >> 5, t = i & 31;
            float s = 0.0f;
#pragma unroll
            for (int c = 0; c < NB; ++c) s += sm.np.bnd[t][c] * fbw[c * 31 + k];
            h_all[(b * 31 + k) * T + t0 + t] = s;
        }
    } else {
        // ================= SS chain =================
        for (int i = tid; i < 34 * 128; i += 512) {
            int cin = i / 34, tr = i % 34;
            int t = t0 + tr - 1;
            sm.ss.xs[tr * 136 + cin] = (t >= 0 && t < T) ? f2bf(cond[(b * 128 + cin) * T + t])
                                                         : (unsigned short)0;
        }
        __syncthreads();
        const int coutb = wave * 16;    // 8 waves x 16 couts = 128
        f4 acc[2] = {};                 // [nv]
#pragma unroll
        for (int tap = 0; tap < 3; ++tap) {
            bf8 aw[4];
#pragma unroll
            for (int q = 0; q < 4; ++q)
                aw[q] = *reinterpret_cast<const bf8*>(
                    wTs + ((tap * 128 + coutb + nfr) * 128 + q * 32 + ko8));
#pragma unroll
            for (int q = 0; q < 4; ++q) {
                bf8 bv0 = *reinterpret_cast<const bf8*>(&sm.ss.xs[(nfr + tap) * 136 + q * 32 + ko8]);
                bf8 bv1 = *reinterpret_cast<const bf8*>(&sm.ss.xs[(nfr + 16 + tap) * 136 + q * 32 + ko8]);
                acc[0] = __builtin_amdgcn_mfma_f32_16x16x32_bf16(aw[q], bv0, acc[0], 0, 0, 0);
                acc[1] = __builtin_amdgcn_mfma_f32_16x16x32_bf16(aw[q], bv1, acc[1], 0, 0, 0);
            }
        }
#pragma unroll
        for (int nv = 0; nv < 2; ++nv) {
            ushort4 pk;
            pk.x = f2bf(leaky(acc[nv][0] + bss[coutb + rb + 0]));
            pk.y = f2bf(leaky(acc[nv][1] + bss[coutb + rb + 1]));
            pk.z = f2bf(leaky(acc[nv][2] + bss[coutb + rb + 2]));
            pk.w = f2bf(leaky(acc[nv][3] + bss[coutb + rb + 3]));
            *reinterpret_cast<ushort4*>(&sm.ss.gs[(nv * 16 + tcol) * 136 + coutb + rb]) = pk;
        }
        __syncthreads();
        if (tid < 128) {
            int c = tid & 3, tl = tid >> 2;   // tl 0..31
            float s = b2ss[c];
#pragma unroll
            for (int kk = 0; kk < 128; kk += 8) {
                uint4 u = *reinterpret_cast<const uint4*>(&sm.ss.gs[tl * 136 + kk]);
                float4 wa = *reinterpret_cast<const float4*>(&w2ss[c * 128 + kk]);
                float4 wb = *reinterpret_cast<const float4*>(&w2ss[c * 128 + kk + 4]);
                s += bflo(u.x) * wa.x + bfhi(u.x) * wa.y
                   + bflo(u.y) * wa.z + bfhi(u.y) * wa.w
                   + bflo(u.z) * wb.x + bfhi(u.z) * wb.y
                   + bflo(u.w) * wb.z + bfhi(u.w) * wb.w;
            }
            sm.ss.sv[tl][c] = s;
        }
        __syncthreads();
        if (tid < 32) {
            float a0 = sm.ss.sv[tid][0], a1v = sm.ss.sv[tid][1];
            float a2v = sm.ss.sv[tid][2], a3v = sm.ss.sv[tid][3];
            float m = fmaxf(fmaxf(a0, a1v), fmaxf(a2v, a3v));
            float e0 = __expf(a0 - m), e1 = __expf(a1v - m);
            float e2 = __expf(a2v - m), e3 = __expf(a3v - m);
            float inv = 1.0f / (e0 + e1 + e2 + e3);
            sm.ss.nws[tid][0] = e0 * inv; sm.ss.nws[tid][1] = e1 * inv;
            sm.ss.nws[tid][2] = e2 * inv; sm.ss.nws[tid][3] = e3 * inv;
        }
        __syncthreads();
        for (int i = tid; i < 63 * 32; i += 512) {
            int k = i >> 5, t = i & 31;
            float s = sm.ss.nws[t][0] * ntf[k] + sm.ss.nws[t][1] * ntf[63 + k]
                    + sm.ss.nws[t][2] * ntf[126 + k] + sm.ss.nws[t][3] * ntf[189 + k];
            g_all[(b * 63 + k) * T + t0 + t] = s;
        }
    }
}

// ---------------- fused sample-rate: 512-sample tile, float2-paired FIR ----------------
__device__ __forceinline__ float interp_T(const float* __restrict__ a, int b, int p) {
    int i0, i1; float w;
    interp_idx(p, i0, i1, w);
    return a[b * T + i0] * (1.0f - w) + a[b * T + i1] * w;
}

__device__ __forceinline__ int refl(int p) {
    return p < 0 ? -p : (p >= L ? 2 * L - 2 - p : p);
}

__global__ __launch_bounds__(512) void k_sr(const float* __restrict__ wn,
                                            const float* __restrict__ g_all,
                                            const float* __restrict__ h_all,
                                            const float* __restrict__ attack,
                                            const float* __restrict__ inten,
                                            float* __restrict__ out) {
    __shared__ float wns[604];    // wn[l0-46 .. l0+557]
    __shared__ float gl[5][64];   // 5 frames (512-span crosses up to 5), rows padded
    __shared__ float hl[5][32];
    __shared__ float flt[542];    // filtered[l0-15 .. l0+526]
    __shared__ float ipl[517];    // intensity_up(l0-3+i)
    __shared__ float gp[516];     // gate_pre(l0-2+i) (reflected)
    const int b = blockIdx.y;
    const int l0 = blockIdx.x * 512;
    const int tid = threadIdx.x;
    for (int i = tid; i < 604; i += 512) {
        int p = l0 - 46 + i;
        wns[i] = (p >= 0 && p < L) ? wn[b * L + p] : 0.0f;
    }
    int fg0, fgu; float wgu;
    interp_idx(l0 - 15, fg0, fgu, wgu);
    // gl (5x63=315) + hl (5x31=155) = 470 items, single pass
    for (int i = tid; i < 470; i += 512) {
        if (i < 315) {
            int j = i / 63, k = i % 63;
            int f = min(fg0 + j, T - 1);
            gl[j][k] = g_all[(b * 63 + k) * T + f];
        } else {
            int i2 = i - 315;
            int j2 = i2 / 31, k2 = i2 % 31;
            int f = min(fg0 + j2, T - 1);
            hl[j2][k2] = h_all[(b * 31 + k2) * T + f];
        }
    }
    for (int i = tid; i < 517; i += 512)
        ipl[i] = interp_T(inten, b, l0 - 3 + i);
    __syncthreads();
    for (int i = tid; i < 516; i += 512) {
        int p = l0 - 2 + i;
        int pr = refl(p);
        float cur = ipl[pr - l0 + 3];
        float prev = (pr == 0) ? cur : ipl[pr - 1 - l0 + 3];
        float diff = cur - prev;
        float ar = interp_T(attack, b, pr);
        float enh = fminf(fmaxf(cur + (diff > 0.1f ? ar * 0.3f : 0.0f), 0.0f), 1.0f);
        gp[i] = (diff > 0.0f) ? enh : cur;
    }
    // flt EXACT zero outside [0,L) (reference zero-pads intermediate `filtered`)
    for (int i = tid; i < 542; i += 512) {
        int p = l0 - 15 + i;
        float v = 0.0f;
        if (p >= 0 && p < L) {
            int i0, i1; float w;
            interp_idx(p, i0, i1, w);
            int d0 = min(max(i0 - fg0, 0), 4);
            int d1 = min(max(i1 - fg0, 0), 4);
            float a0 = 0.0f, a1 = 0.0f;
            const float* g0r = gl[d0];
            const float* g1r = gl[d1];
#pragma unroll
            for (int kp = 0; kp < 31; ++kp) {
                int k = kp * 2;
                float2 G0 = *reinterpret_cast<const float2*>(g0r + k);
                float2 G1 = *reinterpret_cast<const float2*>(g1r + k);
                float x0 = wns[i + k], x1 = wns[i + k + 1];
                a0 += x0 * G0.x; a0 += x1 * G0.y;
                a1 += x0 * G1.x; a1 += x1 * G1.y;
            }
            {   // tap 62
                float x = wns[i + 62];
                a0 += x * g0r[62];
                a1 += x * g1r[62];
            }
            v = (1.0f - w) * a0 + w * a1;
        }
        flt[i] = v;
    }
    __syncthreads();
    const int l = l0 + tid;
    int i0, i1; float w;
    interp_idx(l, i0, i1, w);
    int d0 = min(max(i0 - fg0, 0), 4);
    int d1 = min(max(i1 - fg0, 0), 4);
    float a0 = 0.0f, a1 = 0.0f;
    const float* h0r = hl[d0];
    const float* h1r = hl[d1];
#pragma unroll
    for (int kp = 0; kp < 15; ++kp) {
        int k = kp * 2;
        float2 H0 = *reinterpret_cast<const float2*>(h0r + k);
        float2 H1 = *reinterpret_cast<const float2*>(h1r + k);
        float x0 = flt[tid + k], x1 = flt[tid + k + 1];
        a0 += x0 * H0.x; a0 += x1 * H0.y;
        a1 += x0 * H1.x; a1 += x1 * H1.y;
    }
    {   // tap 30
        float x = flt[tid + 30];
        a0 += x * h0r[30];
        a1 += x * h1r[30];
    }
    float shaped = (1.0f - w) * a0 + w * a1;
    float g5 = (gp[tid] + gp[tid + 1] + gp[tid + 2] + gp[tid + 3] + gp[tid + 4]) * 0.2f;
    out[b * L + l] = shaped * g5;
    out[B * L + b * L + l] = g5;
}

extern "C" void kernel_launch(void* const* d_in, const int* in_sizes, int n_in,
                              void* d_out, int out_size, void* d_ws, size_t ws_size,
                              hipStream_t stream) {
    const float* cond  = (const float*)d_in[0];
    const float* wn    = (const float*)d_in[1];
    const float* np_w1 = (const float*)d_in[2];
    const float* np_b1 = (const float*)d_in[3];
    const float* np_w2 = (const float*)d_in[4];
    const float* np_b2 = (const float*)d_in[5];
    const float* np_w3 = (const float*)d_in[6];
    const float* np_b3 = (const float*)d_in[7];
    const float* ss_w1 = (const float*)d_in[8];
    const float* ss_b1 = (const float*)d_in[9];
    const float* ss_w2 = (const float*)d_in[10];
    const float* ss_b2 = (const float*)d_in[11];
    const float* fb_w  = (const float*)d_in[12];
    const float* nt_w  = (const float*)d_in[13];

    char* p = (char*)d_ws;
    unsigned short* wT1 = (unsigned short*)p; p += 196608;   // [3][256][128] bf16
    unsigned short* wT2 = (unsigned short*)p; p += 393216;   // [3][256][256] bf16
    unsigned short* wTs = (unsigned short*)p; p += 98304;    // [3][128][128] bf16
    float* attack = (float*)p; p += 25600;                   // [8][800]
    float* inten  = (float*)p; p += 25600;                   // [8][800]
    float* g_all  = (float*)p; p += 1612800;                 // [8][63][800]
    float* h_all  = (float*)p; p += 793600;                  // [8][31][800]
    float* out = (float*)d_out;

    k_twm<<<1344, 256, 0, stream>>>(np_w1, np_w2, ss_w1, wT1, wT2, wTs);
    k_mega<<<400, 512, 0, stream>>>(cond, wT1, np_b1, wT2, np_b2, np_w3, np_b3,
                                    fb_w, wTs, ss_b1, ss_w2, ss_b2, nt_w,
                                    h_all, g_all, attack, inten);
    k_sr<<<dim3(375, 8), 512, 0, stream>>>(wn, g_all, h_all, attack, inten, out);
}

// Round 13
// 156.026 us; speedup vs baseline: 1.0981x; 1.0981x over previous
//
#include <hip/hip_runtime.h>
#include <math.h>

static constexpr int B  = 8;
static constexpr int T  = 800;
static constexpr int L  = 192000;
static constexpr int NB = 24;
static constexpr float SCALE = 800.0f / 192000.0f;  // T/L

typedef __bf16 bf8 __attribute__((ext_vector_type(8)));
typedef float  f4  __attribute__((ext_vector_type(4)));

__device__ __forceinline__ float sigf(float x) { return 1.0f / (1.0f + __expf(-x)); }
__device__ __forceinline__ float leaky(float x) { return x >= 0.0f ? x : 0.1f * x; }
__device__ __forceinline__ unsigned short f2bf(float f) {
    unsigned u = __float_as_uint(f);
    u = u + 0x7FFFu + ((u >> 16) & 1u);
    return (unsigned short)(u >> 16);
}
__device__ __forceinline__ float bflo(unsigned u) { return __uint_as_float(u << 16); }
__device__ __forceinline__ float bfhi(unsigned u) { return __uint_as_float(u & 0xffff0000u); }

__device__ __forceinline__ void interp_idx(int l, int& i0, int& i1, float& w) {
    float pos = ((float)l + 0.5f) * SCALE - 0.5f;
    pos = fminf(fmaxf(pos, 0.0f), (float)(T - 1));
    i0 = (int)pos;
    i1 = min(i0 + 1, T - 1);
    w = pos - (float)i0;
}

// ---- weight transpose+cast: conv weights -> [tap][cout][cin] bf16 ----
__global__ __launch_bounds__(256) void k_twm(const float* __restrict__ w1,
                                             const float* __restrict__ w2,
                                             const float* __restrict__ wss,
                                             unsigned short* __restrict__ wT1,
                                             unsigned short* __restrict__ wT2,
                                             unsigned short* __restrict__ wTs) {
    int idx = blockIdx.x * 256 + threadIdx.x;
    if (idx < 98304) {                        // np_w1 [256][128][3]
        int tap = idx / (256 * 128), r = idx % (256 * 128);
        int cout = r / 128, cin = r % 128;
        wT1[idx] = f2bf(w1[(cout * 128 + cin) * 3 + tap]);
    } else if (idx < 98304 + 196608) {        // np_w2 [256][256][3]
        int j = idx - 98304;
        int tap = j / (256 * 256), r = j % (256 * 256);
        int cout = r / 256, cin = r % 256;
        wT2[j] = f2bf(w2[(cout * 256 + cin) * 3 + tap]);
    } else if (idx < 98304 + 196608 + 49152) {// ss_w1 [128][128][3]
        int j = idx - 294912;
        int tap = j / (128 * 128), r = j % (128 * 128);
        int cout = r / 128, cin = r % 128;
        wTs[j] = f2bf(wss[(cout * 128 + cin) * 3 + tap]);
    }
}

// ---- mega (512 thr / 8 waves, 32-col t-tile); grid (25,8,2): blockIdx.x = t-tile
// varies fastest so co-dispatched blocks share b+chain and stream the SAME weights
// (L2-friendly; round-12 1D batch-interleave remap regressed 41.6->56 us) ----
union SMem {
    struct {
        unsigned short xs[50 * 136];     // cond cols t0-2 .. t0+47 (only ..t0+33 used)
        unsigned short h1s[34 * 264];    // h1 cols t0-1 .. t0+32 (zeroed outside [0,T))
        unsigned short h2s[32 * 264];    // h2 cols t0 .. t0+31
        float bnd[32][25];
    } np;
    struct {
        unsigned short xs[34 * 136];     // cond cols t0-1 .. t0+32
        unsigned short gs[32 * 136];
        float sv[32][5];
        float nws[32][5];
    } ss;
};

__global__ __launch_bounds__(512) void k_mega(const float* __restrict__ cond,
                                              const unsigned short* __restrict__ wT1,
                                              const float* __restrict__ b1,
                                              const unsigned short* __restrict__ wT2,
                                              const float* __restrict__ b2np,
                                              const float* __restrict__ w3,
                                              const float* __restrict__ b3,
                                              const float* __restrict__ fbw,
                                              const unsigned short* __restrict__ wTs,
                                              const float* __restrict__ bss,
                                              const float* __restrict__ w2ss,
                                              const float* __restrict__ b2ss,
                                              const float* __restrict__ ntf,
                                              float* __restrict__ h_all,
                                              float* __restrict__ g_all,
                                              float* __restrict__ attack,
                                              float* __restrict__ inten) {
    __shared__ SMem sm;
    const int b = blockIdx.y;
    const int t0 = blockIdx.x * 32;
    const int tid = threadIdx.x;
    const int wave = tid >> 6, lane = tid & 63;   // 8 waves
    const int nfr = lane & 15;
    const int ko8 = (lane >> 4) * 8;
    const int rb = (lane >> 4) * 4;
    const int tcol = lane & 15;

    if (blockIdx.z == 0) {
        // ================= NP chain =================
        for (int i = tid; i < 50 * 128; i += 512) {
            int cin = i / 50, j = i % 50;
            int t = t0 - 2 + j;
            sm.np.xs[j * 136 + cin] = (t >= 0 && t < T) ? f2bf(cond[(b * 128 + cin) * T + t])
                                                        : (unsigned short)0;
        }
        __syncthreads();
        const int coutb = wave * 32;    // 8 waves x 32 couts = 256
        // conv1: 3 n-tiles (output cols t0-1 .. t0+46; first 34 kept), 2 m/wave
        f4 a1[3][2] = {};
#pragma unroll
        for (int tap = 0; tap < 3; ++tap) {
            bf8 aw[2][4];
#pragma unroll
            for (int m = 0; m < 2; ++m)
#pragma unroll
                for (int q = 0; q < 4; ++q)
                    aw[m][q] = *reinterpret_cast<const bf8*>(
                        wT1 + ((tap * 256 + coutb + m * 16 + nfr) * 128 + q * 32 + ko8));
#pragma unroll
            for (int q = 0; q < 4; ++q) {
                bf8 bv0 = *reinterpret_cast<const bf8*>(&sm.np.xs[(nfr + tap) * 136 + q * 32 + ko8]);
                bf8 bv1 = *reinterpret_cast<const bf8*>(&sm.np.xs[(nfr + 16 + tap) * 136 + q * 32 + ko8]);
                bf8 bv2 = *reinterpret_cast<const bf8*>(&sm.np.xs[(nfr + 32 + tap) * 136 + q * 32 + ko8]);
#pragma unroll
                for (int m = 0; m < 2; ++m) {
                    a1[0][m] = __builtin_amdgcn_mfma_f32_16x16x32_bf16(aw[m][q], bv0, a1[0][m], 0, 0, 0);
                    a1[1][m] = __builtin_amdgcn_mfma_f32_16x16x32_bf16(aw[m][q], bv1, a1[1][m], 0, 0, 0);
                    a1[2][m] = __builtin_amdgcn_mfma_f32_16x16x32_bf16(aw[m][q], bv2, a1[2][m], 0, 0, 0);
                }
            }
        }
        // h1 -> LDS; cols outside [0,T) are EXACT zeros (conv2's zero padding)
#pragma unroll
        for (int nt = 0; nt < 3; ++nt) {
            int lcol = nt * 16 + tcol;
            if (lcol < 34) {
                int gcol = t0 - 1 + lcol;
                bool ok = (gcol >= 0 && gcol < T);
#pragma unroll
                for (int m = 0; m < 2; ++m) {
                    ushort4 pk;
                    if (ok) {
                        pk.x = f2bf(leaky(a1[nt][m][0] + b1[coutb + m * 16 + rb + 0]));
                        pk.y = f2bf(leaky(a1[nt][m][1] + b1[coutb + m * 16 + rb + 1]));
                        pk.z = f2bf(leaky(a1[nt][m][2] + b1[coutb + m * 16 + rb + 2]));
                        pk.w = f2bf(leaky(a1[nt][m][3] + b1[coutb + m * 16 + rb + 3]));
                    } else {
                        pk.x = pk.y = pk.z = pk.w = 0;
                    }
                    *reinterpret_cast<ushort4*>(&sm.np.h1s[lcol * 264 + coutb + m * 16 + rb]) = pk;
                }
            }
        }
        __syncthreads();
        // conv2: 256->256, 2 n-tiles x 2 m-tiles; per-tap batched A-loads
        f4 a2[2][2] = {};   // [nv][m]
#pragma unroll
        for (int tap = 0; tap < 3; ++tap) {
            bf8 aw[2][8];
#pragma unroll
            for (int m = 0; m < 2; ++m)
#pragma unroll
                for (int q = 0; q < 8; ++q)
                    aw[m][q] = *reinterpret_cast<const bf8*>(
                        wT2 + ((tap * 256 + coutb + m * 16 + nfr) * 256 + q * 32 + ko8));
#pragma unroll
            for (int q = 0; q < 8; ++q) {
                bf8 bv0 = *reinterpret_cast<const bf8*>(&sm.np.h1s[(nfr + tap) * 264 + q * 32 + ko8]);
                bf8 bv1 = *reinterpret_cast<const bf8*>(&sm.np.h1s[(nfr + 16 + tap) * 264 + q * 32 + ko8]);
#pragma unroll
                for (int m = 0; m < 2; ++m) {
                    a2[0][m] = __builtin_amdgcn_mfma_f32_16x16x32_bf16(aw[m][q], bv0, a2[0][m], 0, 0, 0);
                    a2[1][m] = __builtin_amdgcn_mfma_f32_16x16x32_bf16(aw[m][q], bv1, a2[1][m], 0, 0, 0);
                }
            }
        }
#pragma unroll
        for (int nv = 0; nv < 2; ++nv)
#pragma unroll
            for (int m = 0; m < 2; ++m) {
                ushort4 pk;
                pk.x = f2bf(leaky(a2[nv][m][0] + b2np[coutb + m * 16 + rb + 0]));
                pk.y = f2bf(leaky(a2[nv][m][1] + b2np[coutb + m * 16 + rb + 1]));
                pk.z = f2bf(leaky(a2[nv][m][2] + b2np[coutb + m * 16 + rb + 2]));
                pk.w = f2bf(leaky(a2[nv][m][3] + b2np[coutb + m * 16 + rb + 3]));
                *reinterpret_cast<ushort4*>(&sm.np.h2s[(nv * 16 + tcol) * 264 + coutb + m * 16 + rb]) = pk;
            }
        __syncthreads();
        // head in f32; item i -> (c = i>>5, t = i&31); 864 items
        for (int i = tid; i < 27 * 32; i += 512) {
            int c = i >> 5, t = i & 31;
            float s = b3[c];
            const unsigned short* hp = &sm.np.h2s[t * 264];
            const float* wp3 = w3 + c * 256;
#pragma unroll 4
            for (int kk = 0; kk < 256; kk += 8) {
                uint4 u = *reinterpret_cast<const uint4*>(hp + kk);
                float4 wa = *reinterpret_cast<const float4*>(wp3 + kk);
                float4 wb = *reinterpret_cast<const float4*>(wp3 + kk + 4);
                s += bflo(u.x) * wa.x + bfhi(u.x) * wa.y
                   + bflo(u.y) * wa.z + bfhi(u.y) * wa.w
                   + bflo(u.z) * wb.x + bfhi(u.z) * wb.y
                   + bflo(u.w) * wb.z + bfhi(u.w) * wb.w;
            }
            if (c < 24) sm.np.bnd[t][c] = sigf(s);
            else if (c == 24) attack[b * T + t0 + t] = sigf(s) * 10.0f;
            else if (c == 26) inten[b * T + t0 + t] = sigf(s);
        }
        __syncthreads();
        // h_all[b][k][t] = sum_c bnd[t][c] * fbw[c][k]; 992 items
        for (int i = tid; i < 31 * 32; i += 512) {
            int k = i >> 5, t = i & 31;
            float s = 0.0f;
#pragma unroll
            for (int c = 0; c < NB; ++c) s += sm.np.bnd[t][c] * fbw[c * 31 + k];
            h_all[(b * 31 + k) * T + t0 + t] = s;
        }
    } else {
        // ================= SS chain =================
        for (int i = tid; i < 34 * 128; i += 512) {
            int cin = i / 34, tr = i % 34;
            int t = t0 + tr - 1;
            sm.ss.xs[tr * 136 + cin] = (t >= 0 && t < T) ? f2bf(cond[(b * 128 + cin) * T + t])
                                                         : (unsigned short)0;
        }
        __syncthreads();
        const int coutb = wave * 16;    // 8 waves x 16 couts = 128
        f4 acc[2] = {};                 // [nv]
#pragma unroll
        for (int tap = 0; tap < 3; ++tap) {
            bf8 aw[4];
#pragma unroll
            for (int q = 0; q < 4; ++q)
                aw[q] = *reinterpret_cast<const bf8*>(
                    wTs + ((tap * 128 + coutb + nfr) * 128 + q * 32 + ko8));
#pragma unroll
            for (int q = 0; q < 4; ++q) {
                bf8 bv0 = *reinterpret_cast<const bf8*>(&sm.ss.xs[(nfr + tap) * 136 + q * 32 + ko8]);
                bf8 bv1 = *reinterpret_cast<const bf8*>(&sm.ss.xs[(nfr + 16 + tap) * 136 + q * 32 + ko8]);
                acc[0] = __builtin_amdgcn_mfma_f32_16x16x32_bf16(aw[q], bv0, acc[0], 0, 0, 0);
                acc[1] = __builtin_amdgcn_mfma_f32_16x16x32_bf16(aw[q], bv1, acc[1], 0, 0, 0);
            }
        }
#pragma unroll
        for (int nv = 0; nv < 2; ++nv) {
            ushort4 pk;
            pk.x = f2bf(leaky(acc[nv][0] + bss[coutb + rb + 0]));
            pk.y = f2bf(leaky(acc[nv][1] + bss[coutb + rb + 1]));
            pk.z = f2bf(leaky(acc[nv][2] + bss[coutb + rb + 2]));
            pk.w = f2bf(leaky(acc[nv][3] + bss[coutb + rb + 3]));
            *reinterpret_cast<ushort4*>(&sm.ss.gs[(nv * 16 + tcol) * 136 + coutb + rb]) = pk;
        }
        __syncthreads();
        if (tid < 128) {
            int c = tid & 3, tl = tid >> 2;   // tl 0..31
            float s = b2ss[c];
#pragma unroll
            for (int kk = 0; kk < 128; kk += 8) {
                uint4 u = *reinterpret_cast<const uint4*>(&sm.ss.gs[tl * 136 + kk]);
                float4 wa = *reinterpret_cast<const float4*>(&w2ss[c * 128 + kk]);
                float4 wb = *reinterpret_cast<const float4*>(&w2ss[c * 128 + kk + 4]);
                s += bflo(u.x) * wa.x + bfhi(u.x) * wa.y
                   + bflo(u.y) * wa.z + bfhi(u.y) * wa.w
                   + bflo(u.z) * wb.x + bfhi(u.z) * wb.y
                   + bflo(u.w) * wb.z + bfhi(u.w) * wb.w;
            }
            sm.ss.sv[tl][c] = s;
        }
        __syncthreads();
        if (tid < 32) {
            float a0 = sm.ss.sv[tid][0], a1v = sm.ss.sv[tid][1];
            float a2v = sm.ss.sv[tid][2], a3v = sm.ss.sv[tid][3];
            float m = fmaxf(fmaxf(a0, a1v), fmaxf(a2v, a3v));
            float e0 = __expf(a0 - m), e1 = __expf(a1v - m);
            float e2 = __expf(a2v - m), e3 = __expf(a3v - m);
            float inv = 1.0f / (e0 + e1 + e2 + e3);
            sm.ss.nws[tid][0] = e0 * inv; sm.ss.nws[tid][1] = e1 * inv;
            sm.ss.nws[tid][2] = e2 * inv; sm.ss.nws[tid][3] = e3 * inv;
        }
        __syncthreads();
        for (int i = tid; i < 63 * 32; i += 512) {
            int k = i >> 5, t = i & 31;
            float s = sm.ss.nws[t][0] * ntf[k] + sm.ss.nws[t][1] * ntf[63 + k]
                    + sm.ss.nws[t][2] * ntf[126 + k] + sm.ss.nws[t][3] * ntf[189 + k];
            g_all[(b * 63 + k) * T + t0 + t] = s;
        }
    }
}

// ---------------- fused sample-rate: 512-sample tile, float2-paired FIR ----------------
__device__ __forceinline__ float interp_T(const float* __restrict__ a, int b, int p) {
    int i0, i1; float w;
    interp_idx(p, i0, i1, w);
    return a[b * T + i0] * (1.0f - w) + a[b * T + i1] * w;
}

__device__ __forceinline__ int refl(int p) {
    return p < 0 ? -p : (p >= L ? 2 * L - 2 - p : p);
}

__global__ __launch_bounds__(512) void k_sr(const float* __restrict__ wn,
                                            const float* __restrict__ g_all,
                                            const float* __restrict__ h_all,
                                            const float* __restrict__ attack,
                                            const float* __restrict__ inten,
                                            float* __restrict__ out) {
    __shared__ float wns[604];    // wn[l0-46 .. l0+557]
    __shared__ float gl[5][64];   // 5 frames (512-span crosses up to 5), rows padded
    __shared__ float hl[5][32];
    __shared__ float flt[542];    // filtered[l0-15 .. l0+526]
    __shared__ float ipl[517];    // intensity_up(l0-3+i)
    __shared__ float gp[516];     // gate_pre(l0-2+i) (reflected)
    const int b = blockIdx.y;
    const int l0 = blockIdx.x * 512;
    const int tid = threadIdx.x;
    for (int i = tid; i < 604; i += 512) {
        int p = l0 - 46 + i;
        wns[i] = (p >= 0 && p < L) ? wn[b * L + p] : 0.0f;
    }
    int fg0, fgu; float wgu;
    interp_idx(l0 - 15, fg0, fgu, wgu);
    for (int i = tid; i < 470; i += 512) {
        if (i < 315) {
            int j = i / 63, k = i % 63;
            int f = min(fg0 + j, T - 1);
            gl[j][k] = g_all[(b * 63 + k) * T + f];
        } else {
            int i2 = i - 315;
            int j2 = i2 / 31, k2 = i2 % 31;
            int f = min(fg0 + j2, T - 1);
            hl[j2][k2] = h_all[(b * 31 + k2) * T + f];
        }
    }
    for (int i = tid; i < 517; i += 512)
        ipl[i] = interp_T(inten, b, l0 - 3 + i);
    __syncthreads();
    for (int i = tid; i < 516; i += 512) {
        int p = l0 - 2 + i;
        int pr = refl(p);
        float cur = ipl[pr - l0 + 3];
        float prev = (pr == 0) ? cur : ipl[pr - 1 - l0 + 3];
        float diff = cur - prev;
        float ar = interp_T(attack, b, pr);
        float enh = fminf(fmaxf(cur + (diff > 0.1f ? ar * 0.3f : 0.0f), 0.0f), 1.0f);
        gp[i] = (diff > 0.0f) ? enh : cur;
    }
    // flt EXACT zero outside [0,L) (reference zero-pads intermediate `filtered`)
    for (int i = tid; i < 542; i += 512) {
        int p = l0 - 15 + i;
        float v = 0.0f;
        if (p >= 0 && p < L) {
            int i0, i1; float w;
            interp_idx(p, i0, i1, w);
            int d0 = min(max(i0 - fg0, 0), 4);
            int d1 = min(max(i1 - fg0, 0), 4);
            float a0 = 0.0f, a1 = 0.0f;
            const float* g0r = gl[d0];
            const float* g1r = gl[d1];
#pragma unroll
            for (int kp = 0; kp < 31; ++kp) {
                int k = kp * 2;
                float2 G0 = *reinterpret_cast<const float2*>(g0r + k);
                float2 G1 = *reinterpret_cast<const float2*>(g1r + k);
                float x0 = wns[i + k], x1 = wns[i + k + 1];
                a0 += x0 * G0.x; a0 += x1 * G0.y;
                a1 += x0 * G1.x; a1 += x1 * G1.y;
            }
            {   // tap 62
                float x = wns[i + 62];
                a0 += x * g0r[62];
                a1 += x * g1r[62];
            }
            v = (1.0f - w) * a0 + w * a1;
        }
        flt[i] = v;
    }
    __syncthreads();
    const int l = l0 + tid;
    int i0, i1; float w;
    interp_idx(l, i0, i1, w);
    int d0 = min(max(i0 - fg0, 0), 4);
    int d1 = min(max(i1 - fg0, 0), 4);
    float a0 = 0.0f, a1 = 0.0f;
    const float* h0r = hl[d0];
    const float* h1r = hl[d1];
#pragma unroll
    for (int kp = 0; kp < 15; ++kp) {
        int k = kp * 2;
        float2 H0 = *reinterpret_cast<const float2*>(h0r + k);
        float2 H1 = *reinterpret_cast<const float2*>(h1r + k);
        float x0 = flt[tid + k], x1 = flt[tid + k + 1];
        a0 += x0 * H0.x; a0 += x1 * H0.y;
        a1 += x0 * H1.x; a1 += x1 * H1.y;
    }
    {   // tap 30
        float x = flt[tid + 30];
        a0 += x * h0r[30];
        a1 += x * h1r[30];
    }
    float shaped = (1.0f - w) * a0 + w * a1;
    float g5 = (gp[tid] + gp[tid + 1] + gp[tid + 2] + gp[tid + 3] + gp[tid + 4]) * 0.2f;
    out[b * L + l] = shaped * g5;
    out[B * L + b * L + l] = g5;
}

extern "C" void kernel_launch(void* const* d_in, const int* in_sizes, int n_in,
                              void* d_out, int out_size, void* d_ws, size_t ws_size,
                              hipStream_t stream) {
    const float* cond  = (const float*)d_in[0];
    const float* wn    = (const float*)d_in[1];
    const float* np_w1 = (const float*)d_in[2];
    const float* np_b1 = (const float*)d_in[3];
    const float* np_w2 = (const float*)d_in[4];
    const float* np_b2 = (const float*)d_in[5];
    const float* np_w3 = (const float*)d_in[6];
    const float* np_b3 = (const float*)d_in[7];
    const float* ss_w1 = (const float*)d_in[8];
    const float* ss_b1 = (const float*)d_in[9];
    const float* ss_w2 = (const float*)d_in[10];
    const float* ss_b2 = (const float*)d_in[11];
    const float* fb_w  = (const float*)d_in[12];
    const float* nt_w  = (const float*)d_in[13];

    char* p = (char*)d_ws;
    unsigned short* wT1 = (unsigned short*)p; p += 196608;   // [3][256][128] bf16
    unsigned short* wT2 = (unsigned short*)p; p += 393216;   // [3][256][256] bf16
    unsigned short* wTs = (unsigned short*)p; p += 98304;    // [3][128][128] bf16
    float* attack = (float*)p; p += 25600;                   // [8][800]
    float* inten  = (float*)p; p += 25600;                   // [8][800]
    float* g_all  = (float*)p; p += 1612800;                 // [8][63][800]
    float* h_all  = (float*)p; p += 793600;                  // [8][31][800]
    float* out = (float*)d_out;

    k_twm<<<1344, 256, 0, stream>>>(np_w1, np_w2, ss_w1, wT1, wT2, wTs);
    k_mega<<<dim3(25, 8, 2), 512, 0, stream>>>(cond, wT1, np_b1, wT2, np_b2, np_w3, np_b3,
                                               fb_w, wTs, ss_b1, ss_w2, ss_b2, nt_w,
                                               h_all, g_all, attack, inten);
    k_sr<<<dim3(375, 8), 512, 0, stream>>>(wn, g_all, h_all, attack, inten, out);
}